// Round 1
// baseline (431.198 us; speedup 1.0000x reference)
//
#include <hip/hip_runtime.h>

typedef unsigned short u16;
typedef unsigned int   u32;
typedef __attribute__((ext_vector_type(8))) __bf16 bf16x8;
typedef __attribute__((ext_vector_type(4))) float  f32x4;

#define HW 4096
#define NPOS 65536
#define CH 256
#define MT 512   // number of 128-row M tiles

__device__ __forceinline__ u16 f2bf(float f){
  u32 u = __float_as_uint(f);
  u += 0x7FFFu + ((u >> 16) & 1u);
  return (u16)(u >> 16);
}
__device__ __forceinline__ float bflo(u32 p){ return __uint_as_float(p << 16); }
__device__ __forceinline__ float bfhi(u32 p){ return __uint_as_float(p & 0xFFFF0000u); }

// global_load_lds width=16: per-lane GLOBAL src, wave-uniform LDS dst + lane*16B.
#define GLL16(g, l) __builtin_amdgcn_global_load_lds( \
    (__attribute__((address_space(1))) void*)(g), \
    (__attribute__((address_space(3))) void*)(l), 16, 0, 0)

// ---------------- x plane stats: total, edge rows/cols, corners ----------------
__global__ __launch_bounds__(256) void k_statsx(const float* __restrict__ x, float* __restrict__ stats){
  int bc = blockIdx.x; int tid = threadIdx.x;
  const float* xp = x + (size_t)bc * HW;
  float S=0.f, r0=0.f, r1=0.f, c0=0.f, c1=0.f;
  #pragma unroll
  for (int k=0;k<4;k++){
    int i4 = tid + k*256;
    float4 v = ((const float4*)xp)[i4];
    int pos = i4*4; int h = pos>>6; int wb = pos&63;
    float sv = v.x+v.y+v.z+v.w;
    S += sv;
    if (h==0)  r0 += sv;
    if (h==63) r1 += sv;
    if (wb==0)  c0 += v.x;
    if (wb==60) c1 += v.w;
  }
  __shared__ float red[4][5];
  #pragma unroll
  for (int off=32; off>0; off>>=1){
    S  += __shfl_down(S, off);
    r0 += __shfl_down(r0, off);
    r1 += __shfl_down(r1, off);
    c0 += __shfl_down(c0, off);
    c1 += __shfl_down(c1, off);
  }
  if ((tid & 63) == 0){
    int w = tid >> 6;
    red[w][0]=S; red[w][1]=r0; red[w][2]=r1; red[w][3]=c0; red[w][4]=c1;
  }
  __syncthreads();
  if (tid == 0){
    float* o = stats + (size_t)bc * 9;
    for (int j=0;j<5;j++) o[j] = red[0][j]+red[1][j]+red[2][j]+red[3][j];
    o[5] = xp[0];    // x[0][0]
    o[6] = xp[63];   // x[0][63]
    o[7] = xp[4032]; // x[63][0]
    o[8] = xp[4095]; // x[63][63]
  }
}

// ---------------- fused modulation gate: one block per batch element ----------------
__global__ __launch_bounds__(256) void k_gate(const float* __restrict__ dce,
    const float* __restrict__ stats, const float* __restrict__ wch,
    const float* __restrict__ w_dce, const float* __restrict__ b_dce,
    const float* __restrict__ w_sh, const float* __restrict__ b_sh,
    const float* __restrict__ w_ex, const float* __restrict__ b_ex,
    float* __restrict__ modb){
  int b = blockIdx.x, tid = threadIdx.x;
  __shared__ float pl[128];
  __shared__ float mbuf[256];
  __shared__ float hbuf[128];
  __shared__ float ptmp[256];
  {
    int k = tid & 127, half = tid >> 7;
    const float* p = dce + (size_t)b*12800 + half*50*128 + k;
    float s = 0.f;
    #pragma unroll 5
    for (int l=0;l<50;l++) s += p[l*128];
    ptmp[tid] = s;
  }
  __syncthreads();
  if (tid < 128) pl[tid] = (ptmp[tid] + ptmp[tid+128]) * 0.01f;
  __syncthreads();
  {
    int c = tid;
    const float* st = stats + (size_t)(b*256+c)*9;
    float S=st[0], r0=st[1], r1=st[2], cc0=st[3], cc1=st[4];
    float x00=st[5], x0W=st[6], xH0=st[7], xHW=st[8];
    float acc = 0.f;
    #pragma unroll
    for (int t=0;t<9;t++){
      int dh = t/3 - 1, dw = t%3 - 1;
      float R = (dh==1)? r0 : (dh==-1)? r1 : 0.f;
      float Cc = (dw==1)? cc0 : (dw==-1)? cc1 : 0.f;
      float X = 0.f;
      if (dh==1 && dw==1) X = x00;
      else if (dh==1 && dw==-1) X = x0W;
      else if (dh==-1 && dw==1) X = xH0;
      else if (dh==-1 && dw==-1) X = xHW;
      acc += wch[c*9+t] * (S - R - Cc + X);
    }
    float sp_ = acc * (1.f/4096.f);
    float dp = b_dce[c];
    const float4* wr = (const float4*)(w_dce + c*128);
    #pragma unroll 8
    for (int k4=0;k4<32;k4++){
      float4 w4 = wr[k4];
      dp += w4.x*pl[k4*4] + w4.y*pl[k4*4+1] + w4.z*pl[k4*4+2] + w4.w*pl[k4*4+3];
    }
    mbuf[c] = sp_ * dp;
  }
  __syncthreads();
  if (tid < 128){
    int j = tid;
    float acc = b_sh[j];
    const float4* wr = (const float4*)(w_sh + j*256);
    #pragma unroll 8
    for (int k4=0;k4<64;k4++){
      float4 w4 = wr[k4];
      acc += w4.x*mbuf[k4*4] + w4.y*mbuf[k4*4+1] + w4.z*mbuf[k4*4+2] + w4.w*mbuf[k4*4+3];
    }
    hbuf[j] = fmaxf(acc, 0.f);
  }
  __syncthreads();
  {
    int c = tid;
    float acc = b_ex[c];
    const float4* wr = (const float4*)(w_ex + c*128);
    #pragma unroll 8
    for (int k4=0;k4<32;k4++){
      float4 w4 = wr[k4];
      acc += w4.x*hbuf[k4*4] + w4.y*hbuf[k4*4+1] + w4.z*hbuf[k4*4+2] + w4.w*hbuf[k4*4+3];
    }
    modb[b*256+c] = 1.f/(1.f + __expf(-acc));
  }
}

// ---------------- merged weight transforms to bf16 ----------------
__global__ __launch_bounds__(256) void k_wprep(const float* __restrict__ w1,
    const float* __restrict__ wsc, const float* __restrict__ w2,
    u16* __restrict__ w1t, u16* __restrict__ wsct, u16* __restrict__ w2t){
  int bx = blockIdx.x, ci = threadIdx.x;
  if (bx < 2304){
    int co = bx / 9, t = bx - co*9;
    w1t[(size_t)co*2304 + t*256 + ci] = f2bf(w1[(size_t)(co*256+ci)*9 + t]);
  } else if (bx < 2560){
    int i = (bx-2304)*256 + ci;
    wsct[i] = f2bf(wsc[i]);
  } else {
    int i = (bx-2560)*256 + ci;
    w2t[i] = f2bf(w2[i]);
  }
}

// ---------------- xm = x*mod, NCHW f32 -> NHWC bf16 ----------------
__global__ __launch_bounds__(256) void k_xm(const float* __restrict__ x, const float* __restrict__ modb,
                                            u16* __restrict__ xm){
  __shared__ __attribute__((aligned(16))) u16 tile[64*266];
  int pt = blockIdx.x, ct = blockIdx.y, tid = threadIdx.x;
  size_t P0 = (size_t)pt * 256;
  int b = pt >> 4;
  int rem = (pt & 15) << 8;
  int C0 = ct << 6;
  {
    int c = tid >> 2, q = tid & 3;
    const float* xp = x + ((size_t)(b*256 + C0 + c))*HW + rem;
    float mv = modb[b*256 + C0 + c];
    #pragma unroll
    for (int k=0;k<16;k++){
      int pos = q*64 + k*4;
      float4 v = *(const float4*)(xp + pos);
      u32 w0 = (u32)f2bf(v.x*mv) | ((u32)f2bf(v.y*mv) << 16);
      u32 w1 = (u32)f2bf(v.z*mv) | ((u32)f2bf(v.w*mv) << 16);
      u32* dst = (u32*)&tile[c*266 + pos];
      dst[0] = w0; dst[1] = w1;
    }
  }
  __syncthreads();
  {
    int g = tid & 7, p0 = tid >> 3;
    #pragma unroll
    for (int k=0;k<8;k++){
      int pos = p0 + k*32;
      u32 v0 = tile[(g*8+0)*266 + pos], v1 = tile[(g*8+1)*266 + pos];
      u32 v2 = tile[(g*8+2)*266 + pos], v3 = tile[(g*8+3)*266 + pos];
      u32 v4 = tile[(g*8+4)*266 + pos], v5 = tile[(g*8+5)*266 + pos];
      u32 v6 = tile[(g*8+6)*266 + pos], v7 = tile[(g*8+7)*266 + pos];
      uint4 pk;
      pk.x = v0 | (v1<<16); pk.y = v2 | (v3<<16);
      pk.z = v4 | (v5<<16); pk.w = v6 | (v7<<16);
      *(uint4*)(xm + (P0+pos)*CH + C0 + g*8) = pk;
    }
  }
}

// ---------------- GEMM epilogue: store y bf16 + per-mtile channel partials ----------------
// psum/psq layout: [channel][mtile] (MT stride) so k_bnstat reads coalesced.
__device__ __forceinline__ void epilogue_store(f32x4 (&acc)[4][4], int P0, int N0, int wm, int wn,
    int l15, int quad, int tid, int mt_blk, u16* __restrict__ y,
    float* __restrict__ psum, float* __restrict__ psq, float* redbuf){
  #pragma unroll
  for (int i=0;i<4;i++){
    int m = wm*64 + i*16 + quad*4;
    #pragma unroll
    for (int j=0;j<4;j++){
      int n = wn*64 + j*16 + l15;
      size_t base = ((size_t)(P0 + m))*CH + N0 + n;
      #pragma unroll
      for (int r=0;r<4;r++)
        y[base + (size_t)r*CH] = f2bf(acc[i][j][r]);
    }
  }
  #pragma unroll
  for (int j=0;j<4;j++){
    float a=0.f, b=0.f;
    #pragma unroll
    for (int i=0;i<4;i++)
      #pragma unroll
      for (int r=0;r<4;r++){ float v = acc[i][j][r]; a += v; b += v*v; }
    a += __shfl_xor(a,16); b += __shfl_xor(b,16);
    a += __shfl_xor(a,32); b += __shfl_xor(b,32);
    if (quad==0){
      int idx = (((wn*2+wm)*4 + j)*16 + l15)*2;
      redbuf[idx] = a; redbuf[idx+1] = b;
    }
  }
  __syncthreads();
  if (tid < 128){
    int n = tid; int wnn = n>>6, ntj=(n>>4)&3, li=n&15;
    int i0 = (((wnn*2+0)*4 + ntj)*16 + li)*2;
    int i1 = (((wnn*2+1)*4 + ntj)*16 + li)*2;
    psum[(size_t)(N0 + n)*MT + mt_blk] = redbuf[i0]   + redbuf[i1];
    psq [(size_t)(N0 + n)*MT + mt_blk] = redbuf[i0+1] + redbuf[i1+1];
  }
}

// ---------------- conv3x3 implicit GEMM ----------------
// K=32/barrier, 2x4096 u16 dbuf. R5 lesson: do NOT widen to K=64 (VGPR spill).
// R6 (this round): staging via global_load_lds width=16 (m151: reg-staged 646 TF
// vs gload_lds 874 TF on this exact structure). LDS layout stays LINEAR (the
// linear slot order == tid*16B == lane order, as gload_lds requires); the XOR
// swizzle is applied on the GLOBAL source address (cgs) and on the read side —
// both-sides-or-neither, rule #21.
__global__ __launch_bounds__(256) void k_conv3(const u16* __restrict__ xm, const u16* __restrict__ w1t,
    u16* __restrict__ y, float* __restrict__ psum, float* __restrict__ psq, const u16* __restrict__ zp){
  __shared__ __attribute__((aligned(16))) u16 As[2*4096];
  __shared__ __attribute__((aligned(16))) u16 Bs[2*4096];
  __shared__ __attribute__((aligned(16))) float redbuf[512];
  int bx = blockIdx.x;
  int mt_blk = ((bx >> 4) << 3) | (bx & 7);
  int nt_blk = (bx >> 3) & 1;
  int tid = threadIdx.x;
  int lane = tid & 63, wave = tid >> 6;
  int wm = wave & 1, wn = wave >> 1;
  int l15 = lane & 15, quad = lane >> 4;
  int P0 = mt_blk*128, N0 = nt_blk*128;
  int prow = tid >> 2, cg = tid & 3;
  // pre-swizzled source column-group: LDS slot (prow,cg) must hold src cg^s(prow)
  int cgs = cg ^ (prow & 3) ^ ((prow >> 2) & 3);
  int rdsw = (quad ^ (l15 & 3) ^ ((l15 >> 2) & 3)) * 8;
  int rA[4], rB[4];
  #pragma unroll
  for (int i=0;i<4;i++){
    rA[i] = (wm*64 + i*16 + l15)*32 + rdsw;
    rB[i] = (wn*64 + i*16 + l15)*32 + rdsw;
  }
  const u16* b0base = w1t + (size_t)(N0 + prow)*2304 + cgs*8;
  const u16* b1base = w1t + (size_t)(N0 + prow + 64)*2304 + cgs*8;
  int P_0 = P0 + prow, P_1 = P0 + prow + 64;
  int h_0 = (P_0 >> 6) & 63, w_0 = P_0 & 63, bi0 = P_0 >> 12;
  int h_1 = (P_1 >> 6) & 63, w_1 = P_1 & 63, bi1 = P_1 >> 12;

  // wave-uniform LDS destination bases (u16 units; wave*512 u16 = 1024B per wave)
  u16* lA0 = As + wave*512;
  u16* lA1 = As + 2048 + wave*512;
  u16* lB0 = Bs + wave*512;
  u16* lB1 = Bs + 2048 + wave*512;

  f32x4 acc[4][4];
  f32x4 zz = {0.f,0.f,0.f,0.f};
  #pragma unroll
  for (int i=0;i<4;i++)
    #pragma unroll
    for (int j=0;j<4;j++) acc[i][j] = zz;

  auto aptr0 = [&](int t)->const u16*{
    int dh = t/3 - 1, dw = t%3 - 1;
    int h2 = h_0 + dh, w2 = w_0 + dw;
    return (((unsigned)h2 < 64u) && ((unsigned)w2 < 64u))
        ? xm + (((size_t)bi0*HW + h2*64 + w2)*CH) + cgs*8 : zp + cgs*8;
  };
  auto aptr1 = [&](int t)->const u16*{
    int dh = t/3 - 1, dw = t%3 - 1;
    int h2 = h_1 + dh, w2 = w_1 + dw;
    return (((unsigned)h2 < 64u) && ((unsigned)w2 < 64u))
        ? xm + (((size_t)bi1*HW + h2*64 + w2)*CH) + cgs*8 : zp + cgs*8;
  };
  auto stage = [&](const u16* a0, const u16* a1, const u16* b0, const u16* b1, int bo){
    GLL16(a0, lA0 + bo);
    GLL16(a1, lA1 + bo);
    GLL16(b0, lB0 + bo);
    GLL16(b1, lB1 + bo);
  };

  const u16 *pa0 = aptr0(0), *pa1 = aptr1(0);
  const u16 *pb0 = b0base,   *pb1 = b1base;
  stage(pa0, pa1, pb0, pb1, 0);          // ks=0 -> buf0
  __syncthreads();                       // drains vmcnt(0): buf0 ready

  for (int t=0; t<9; t++){
    #pragma unroll
    for (int ci=0; ci<8; ci++){
      const int bo = (ci & 1) * 4096;    // ks=t*8+ci; buf parity == ci&1
      // issue next K-step's staging into the other buffer (in flight across compute)
      if (ci < 7){
        int off = (ci+1)*32;
        stage(pa0+off, pa1+off, pb0+off, pb1+off, bo ^ 4096);
      } else if (t < 8){
        pa0 = aptr0(t+1); pa1 = aptr1(t+1);
        pb0 = b0base + (t+1)*256; pb1 = b1base + (t+1)*256;
        stage(pa0, pa1, pb0, pb1, bo ^ 4096);
      }
      bf16x8 af[4], bv[4];
      #pragma unroll
      for (int i=0;i<4;i++) af[i] = *(const bf16x8*)&As[bo + rA[i]];
      #pragma unroll
      for (int i=0;i<4;i++) bv[i] = *(const bf16x8*)&Bs[bo + rB[i]];
      #pragma unroll
      for (int i=0;i<4;i++)
        #pragma unroll
        for (int j=0;j<4;j++)
          acc[i][j] = __builtin_amdgcn_mfma_f32_16x16x32_bf16(af[i], bv[j], acc[i][j], 0, 0, 0);
      __syncthreads();                   // drains vmcnt(0): next buffer ready
    }
  }
  epilogue_store(acc, P0, N0, wm, wn, l15, quad, tid, mt_blk, y, psum, psq, redbuf);
}

// ---------------- 1x1 conv GEMM (sc and conv2), gload_lds-staged dbuf ----------------
__global__ __launch_bounds__(256) void k_gemm1x1(const u16* __restrict__ A, const u16* __restrict__ Bw,
    u16* __restrict__ y, float* __restrict__ psum, float* __restrict__ psq){
  __shared__ __attribute__((aligned(16))) u16 As[2*4096];
  __shared__ __attribute__((aligned(16))) u16 Bs[2*4096];
  __shared__ __attribute__((aligned(16))) float redbuf[512];
  int bx = blockIdx.x;
  int mt_blk = ((bx >> 4) << 3) | (bx & 7);
  int nt_blk = (bx >> 3) & 1;
  int tid = threadIdx.x;
  int lane = tid & 63, wave = tid >> 6;
  int wm = wave & 1, wn = wave >> 1;
  int l15 = lane & 15, quad = lane >> 4;
  int P0 = mt_blk*128, N0 = nt_blk*128;
  int prow = tid >> 2, cg = tid & 3;
  int cgs = cg ^ (prow & 3) ^ ((prow >> 2) & 3);
  int rdsw = (quad ^ (l15 & 3) ^ ((l15 >> 2) & 3)) * 8;
  int rA[4], rB[4];
  #pragma unroll
  for (int i=0;i<4;i++){
    rA[i] = (wm*64 + i*16 + l15)*32 + rdsw;
    rB[i] = (wn*64 + i*16 + l15)*32 + rdsw;
  }
  const u16* a0p = A  + ((size_t)(P0 + prow))*CH + cgs*8;
  const u16* a1p = A  + ((size_t)(P0 + prow + 64))*CH + cgs*8;
  const u16* b0p = Bw + ((size_t)(N0 + prow))*CH + cgs*8;
  const u16* b1p = Bw + ((size_t)(N0 + prow + 64))*CH + cgs*8;

  u16* lA0 = As + wave*512;
  u16* lA1 = As + 2048 + wave*512;
  u16* lB0 = Bs + wave*512;
  u16* lB1 = Bs + 2048 + wave*512;

  f32x4 acc[4][4];
  f32x4 zz = {0.f,0.f,0.f,0.f};
  #pragma unroll
  for (int i=0;i<4;i++)
    #pragma unroll
    for (int j=0;j<4;j++) acc[i][j] = zz;

  auto stage = [&](int off, int bo){
    GLL16(a0p + off, lA0 + bo);
    GLL16(a1p + off, lA1 + bo);
    GLL16(b0p + off, lB0 + bo);
    GLL16(b1p + off, lB1 + bo);
  };

  stage(0, 0);
  __syncthreads();

  #pragma unroll
  for (int ci=0; ci<8; ci++){
    const int bo = (ci & 1) * 4096;
    if (ci < 7) stage((ci+1)*32, bo ^ 4096);
    bf16x8 af[4], bv[4];
    #pragma unroll
    for (int i=0;i<4;i++) af[i] = *(const bf16x8*)&As[bo + rA[i]];
    #pragma unroll
    for (int i=0;i<4;i++) bv[i] = *(const bf16x8*)&Bs[bo + rB[i]];
    #pragma unroll
    for (int i=0;i<4;i++)
      #pragma unroll
      for (int j=0;j<4;j++)
        acc[i][j] = __builtin_amdgcn_mfma_f32_16x16x32_bf16(af[i], bv[j], acc[i][j], 0, 0, 0);
    __syncthreads();
  }
  epilogue_store(acc, P0, N0, wm, wn, l15, quad, tid, mt_blk, y, psum, psq, redbuf);
}

// ---------------- BN stat finalize: one block per channel, coalesced ----------------
__global__ __launch_bounds__(64) void k_bnstat(const float* __restrict__ psum, const float* __restrict__ psq,
    const float* __restrict__ g, const float* __restrict__ be,
    float* __restrict__ scale, float* __restrict__ shift){
  int c = blockIdx.x, t = threadIdx.x;
  const float* ps = psum + (size_t)c*MT;
  const float* pq = psq  + (size_t)c*MT;
  float s=0.f, q=0.f;
  #pragma unroll
  for (int i=0;i<8;i++){ s += ps[t + i*64]; q += pq[t + i*64]; }
  #pragma unroll
  for (int off=32; off>0; off>>=1){
    s += __shfl_down(s, off);
    q += __shfl_down(q, off);
  }
  if (t == 0){
    float mean = s * (1.f/65536.f);
    float var  = q * (1.f/65536.f) - mean*mean;
    float rstd = rsqrtf(var + 1e-5f);
    float sc = g[c]*rstd;
    scale[c] = sc;
    shift[c] = be[c] - mean*sc;
  }
}

// ---------------- bb1 = silu(bn1(y1)) elementwise on NHWC bf16 ----------------
__global__ __launch_bounds__(256) void k_bb(const u16* __restrict__ y1, const float* __restrict__ sc1,
    const float* __restrict__ sh1, u16* __restrict__ bb){
  __shared__ float sc[256], sh[256];
  int tid = threadIdx.x;
  sc[tid] = sc1[tid]; sh[tid] = sh1[tid];
  __syncthreads();
  size_t i = ((size_t)blockIdx.x*256 + tid)*8;
  int c0 = (int)(i & 255);
  uint4 v = *(const uint4*)(y1 + i);
  u32 a[4] = {v.x, v.y, v.z, v.w};
  u32 o[4];
  #pragma unroll
  for (int p=0;p<4;p++){
    float zl = sc[c0+2*p]*bflo(a[p]) + sh[c0+2*p];
    float zh = sc[c0+2*p+1]*bfhi(a[p]) + sh[c0+2*p+1];
    float ol = zl/(1.f+__expf(-zl));
    float oh = zh/(1.f+__expf(-zh));
    o[p] = (u32)f2bf(ol) | ((u32)f2bf(oh) << 16);
  }
  uint4 w; w.x=o[0]; w.y=o[1]; w.z=o[2]; w.w=o[3];
  *(uint4*)(bb + i) = w;
}

// ---------------- out = silu(bn2(y2)+bns(ysc)), NHWC bf16 -> NCHW f32 ----------------
__global__ __launch_bounds__(256) void k_final(const u16* __restrict__ y2, const u16* __restrict__ ysc,
    const float* __restrict__ sc2, const float* __restrict__ sh2,
    const float* __restrict__ scs, const float* __restrict__ shs,
    float* __restrict__ out){
  __shared__ __attribute__((aligned(16))) float tile[64*257];
  __shared__ float l2s[64], l2h[64], lss[64], lsh[64];
  int pt = blockIdx.x, ct = blockIdx.y, tid = threadIdx.x;
  int C0 = ct << 6;
  if (tid < 64){ l2s[tid]=sc2[C0+tid]; l2h[tid]=sh2[C0+tid]; lss[tid]=scs[C0+tid]; lsh[tid]=shs[C0+tid]; }
  __syncthreads();
  size_t P0 = (size_t)pt * 256;
  int b = pt >> 4; int rem = (pt & 15) << 8;
  {
    int g = tid & 7, p0 = tid >> 3;
    for (int k=0;k<8;k++){
      int pos = p0 + k*32;
      size_t off = (P0+pos)*CH + C0 + g*8;
      uint4 va = *(const uint4*)(y2 + off);
      uint4 vb = *(const uint4*)(ysc + off);
      u32 aa[4] = {va.x,va.y,va.z,va.w};
      u32 bv[4] = {vb.x,vb.y,vb.z,vb.w};
      #pragma unroll
      for (int p=0;p<4;p++){
        int c = g*8 + 2*p;
        float z0 = l2s[c]*bflo(aa[p]) + l2h[c] + lss[c]*bflo(bv[p]) + lsh[c];
        float z1 = l2s[c+1]*bfhi(aa[p]) + l2h[c+1] + lss[c+1]*bfhi(bv[p]) + lsh[c+1];
        tile[c*257 + pos]     = z0/(1.f+__expf(-z0));
        tile[(c+1)*257 + pos] = z1/(1.f+__expf(-z1));
      }
    }
  }
  __syncthreads();
  {
    int c = tid >> 2, q = tid & 3;
    float* op = out + ((size_t)(b*256 + C0 + c))*HW + rem;
    #pragma unroll
    for (int k=0;k<16;k++){
      int pos = q*64 + k*4;
      float4 v;
      v.x = tile[c*257 + pos];
      v.y = tile[c*257 + pos + 1];
      v.z = tile[c*257 + pos + 2];
      v.w = tile[c*257 + pos + 3];
      *(float4*)(op + pos) = v;
    }
  }
}

extern "C" void kernel_launch(void* const* d_in, const int* in_sizes, int n_in,
                              void* d_out, int out_size, void* d_ws, size_t ws_size,
                              hipStream_t stream){
  const float* x     = (const float*)d_in[0];
  const float* dce   = (const float*)d_in[1];
  const float* w_dce = (const float*)d_in[2];
  const float* b_dce = (const float*)d_in[3];
  const float* w_ch  = (const float*)d_in[4];
  const float* w_sh  = (const float*)d_in[5];
  const float* b_sh  = (const float*)d_in[6];
  const float* w_ex  = (const float*)d_in[7];
  const float* b_ex  = (const float*)d_in[8];
  const float* w_c1  = (const float*)d_in[9];
  const float* g1    = (const float*)d_in[10];
  const float* be1   = (const float*)d_in[11];
  const float* w_c2  = (const float*)d_in[12];
  const float* g2    = (const float*)d_in[13];
  const float* be2   = (const float*)d_in[14];
  const float* w_s   = (const float*)d_in[15];
  const float* gs    = (const float*)d_in[16];
  const float* bes   = (const float*)d_in[17];
  float* out = (float*)d_out;
  char* ws = (char*)d_ws;

  const size_t NB = (size_t)NPOS*CH*2;   // 32 MiB per bf16 tensor
  u16* xm  = (u16*)(ws);
  u16* y1  = (u16*)(ws + NB);
  u16* ysc = (u16*)(ws + 2*NB);
  u16* bb  = (u16*)(ws + 3*NB);
  char* p = ws + 4*NB;
  u16* w1t   = (u16*)p; p += (size_t)256*2304*2;
  u16* wsct  = (u16*)p; p += (size_t)256*256*2;
  u16* w2t   = (u16*)p; p += (size_t)256*256*2;
  float* statsx = (float*)p; p += (size_t)16*256*9*4;
  float* modb   = (float*)p; p += (size_t)16*256*4;
  float* p1s = (float*)p; p += (size_t)MT*256*4;
  float* p1q = (float*)p; p += (size_t)MT*256*4;
  float* pss = (float*)p; p += (size_t)MT*256*4;
  float* psqv= (float*)p; p += (size_t)MT*256*4;
  float* p2s = (float*)p; p += (size_t)MT*256*4;
  float* p2q = (float*)p; p += (size_t)MT*256*4;
  float* bn1sc = (float*)p; p += 1024;
  float* bn1sh = (float*)p; p += 1024;
  float* bnssc = (float*)p; p += 1024;
  float* bnssh = (float*)p; p += 1024;
  float* bn2sc = (float*)p; p += 1024;
  float* bn2sh = (float*)p; p += 1024;
  u16* zp = (u16*)p; p += 4096;

  hipMemsetAsync(zp, 0, 4096, stream);
  k_statsx<<<4096, 256, 0, stream>>>(x, statsx);
  k_wprep<<<2816, 256, 0, stream>>>(w_c1, w_s, w_c2, w1t, wsct, w2t);
  k_gate<<<16, 256, 0, stream>>>(dce, statsx, w_ch, w_dce, b_dce, w_sh, b_sh, w_ex, b_ex, modb);
  k_xm<<<dim3(256,4), 256, 0, stream>>>(x, modb, xm);
  k_conv3<<<1024, 256, 0, stream>>>(xm, w1t, y1, p1s, p1q, zp);
  k_bnstat<<<256, 64, 0, stream>>>(p1s, p1q, g1, be1, bn1sc, bn1sh);
  k_bb<<<8192, 256, 0, stream>>>(y1, bn1sc, bn1sh, bb);
  k_gemm1x1<<<1024, 256, 0, stream>>>(xm, wsct, ysc, pss, psqv);
  k_bnstat<<<256, 64, 0, stream>>>(pss, psqv, gs, bes, bnssc, bnssh);
  k_gemm1x1<<<1024, 256, 0, stream>>>(bb, w2t, y1 /*=y2*/, p2s, p2q);
  k_bnstat<<<256, 64, 0, stream>>>(p2s, p2q, g2, be2, bn2sc, bn2sh);
  k_final<<<dim3(256,4), 256, 0, stream>>>(y1, ysc, bn2sc, bn2sh, bnssc, bnssh, out);
}

// Round 2
// 425.627 us; speedup vs baseline: 1.0131x; 1.0131x over previous
//
#include <hip/hip_runtime.h>

typedef unsigned short u16;
typedef unsigned int   u32;
typedef __attribute__((ext_vector_type(8))) __bf16 bf16x8;
typedef __attribute__((ext_vector_type(4))) float  f32x4;

#define HW 4096
#define NPOS 65536
#define CH 256
#define MT 512   // number of 128-row M tiles

__device__ __forceinline__ u16 f2bf(float f){
  u32 u = __float_as_uint(f);
  u += 0x7FFFu + ((u >> 16) & 1u);
  return (u16)(u >> 16);
}
__device__ __forceinline__ float bflo(u32 p){ return __uint_as_float(p << 16); }
__device__ __forceinline__ float bfhi(u32 p){ return __uint_as_float(p & 0xFFFF0000u); }

// global_load_lds width=16: per-lane GLOBAL src, wave-uniform LDS dst + lane*16B.
#define GLL16(g, l) __builtin_amdgcn_global_load_lds( \
    (__attribute__((address_space(1))) void*)(g), \
    (__attribute__((address_space(3))) void*)(l), 16, 0, 0)

// counted waitcnt + raw barrier (NO vmcnt(0) drain in main loop — T4)
#define VM4() asm volatile("s_waitcnt vmcnt(4)" ::: "memory")
#define VM0() asm volatile("s_waitcnt vmcnt(0)" ::: "memory")
#define RBAR() do { __builtin_amdgcn_s_barrier(); __builtin_amdgcn_sched_barrier(0); } while(0)

// ---------------- x plane stats: total, edge rows/cols, corners ----------------
__global__ __launch_bounds__(256) void k_statsx(const float* __restrict__ x, float* __restrict__ stats){
  int bc = blockIdx.x; int tid = threadIdx.x;
  const float* xp = x + (size_t)bc * HW;
  float S=0.f, r0=0.f, r1=0.f, c0=0.f, c1=0.f;
  #pragma unroll
  for (int k=0;k<4;k++){
    int i4 = tid + k*256;
    float4 v = ((const float4*)xp)[i4];
    int pos = i4*4; int h = pos>>6; int wb = pos&63;
    float sv = v.x+v.y+v.z+v.w;
    S += sv;
    if (h==0)  r0 += sv;
    if (h==63) r1 += sv;
    if (wb==0)  c0 += v.x;
    if (wb==60) c1 += v.w;
  }
  __shared__ float red[4][5];
  #pragma unroll
  for (int off=32; off>0; off>>=1){
    S  += __shfl_down(S, off);
    r0 += __shfl_down(r0, off);
    r1 += __shfl_down(r1, off);
    c0 += __shfl_down(c0, off);
    c1 += __shfl_down(c1, off);
  }
  if ((tid & 63) == 0){
    int w = tid >> 6;
    red[w][0]=S; red[w][1]=r0; red[w][2]=r1; red[w][3]=c0; red[w][4]=c1;
  }
  __syncthreads();
  if (tid == 0){
    float* o = stats + (size_t)bc * 9;
    for (int j=0;j<5;j++) o[j] = red[0][j]+red[1][j]+red[2][j]+red[3][j];
    o[5] = xp[0];    // x[0][0]
    o[6] = xp[63];   // x[0][63]
    o[7] = xp[4032]; // x[63][0]
    o[8] = xp[4095]; // x[63][63]
  }
}

// ---------------- fused modulation gate: one block per batch element ----------------
__global__ __launch_bounds__(256) void k_gate(const float* __restrict__ dce,
    const float* __restrict__ stats, const float* __restrict__ wch,
    const float* __restrict__ w_dce, const float* __restrict__ b_dce,
    const float* __restrict__ w_sh, const float* __restrict__ b_sh,
    const float* __restrict__ w_ex, const float* __restrict__ b_ex,
    float* __restrict__ modb){
  int b = blockIdx.x, tid = threadIdx.x;
  __shared__ float pl[128];
  __shared__ float mbuf[256];
  __shared__ float hbuf[128];
  __shared__ float ptmp[256];
  {
    int k = tid & 127, half = tid >> 7;
    const float* p = dce + (size_t)b*12800 + half*50*128 + k;
    float s = 0.f;
    #pragma unroll 5
    for (int l=0;l<50;l++) s += p[l*128];
    ptmp[tid] = s;
  }
  __syncthreads();
  if (tid < 128) pl[tid] = (ptmp[tid] + ptmp[tid+128]) * 0.01f;
  __syncthreads();
  {
    int c = tid;
    const float* st = stats + (size_t)(b*256+c)*9;
    float S=st[0], r0=st[1], r1=st[2], cc0=st[3], cc1=st[4];
    float x00=st[5], x0W=st[6], xH0=st[7], xHW=st[8];
    float acc = 0.f;
    #pragma unroll
    for (int t=0;t<9;t++){
      int dh = t/3 - 1, dw = t%3 - 1;
      float R = (dh==1)? r0 : (dh==-1)? r1 : 0.f;
      float Cc = (dw==1)? cc0 : (dw==-1)? cc1 : 0.f;
      float X = 0.f;
      if (dh==1 && dw==1) X = x00;
      else if (dh==1 && dw==-1) X = x0W;
      else if (dh==-1 && dw==1) X = xH0;
      else if (dh==-1 && dw==-1) X = xHW;
      acc += wch[c*9+t] * (S - R - Cc + X);
    }
    float sp_ = acc * (1.f/4096.f);
    float dp = b_dce[c];
    const float4* wr = (const float4*)(w_dce + c*128);
    #pragma unroll 8
    for (int k4=0;k4<32;k4++){
      float4 w4 = wr[k4];
      dp += w4.x*pl[k4*4] + w4.y*pl[k4*4+1] + w4.z*pl[k4*4+2] + w4.w*pl[k4*4+3];
    }
    mbuf[c] = sp_ * dp;
  }
  __syncthreads();
  if (tid < 128){
    int j = tid;
    float acc = b_sh[j];
    const float4* wr = (const float4*)(w_sh + j*256);
    #pragma unroll 8
    for (int k4=0;k4<64;k4++){
      float4 w4 = wr[k4];
      acc += w4.x*mbuf[k4*4] + w4.y*mbuf[k4*4+1] + w4.z*mbuf[k4*4+2] + w4.w*mbuf[k4*4+3];
    }
    hbuf[j] = fmaxf(acc, 0.f);
  }
  __syncthreads();
  {
    int c = tid;
    float acc = b_ex[c];
    const float4* wr = (const float4*)(w_ex + c*128);
    #pragma unroll 8
    for (int k4=0;k4<32;k4++){
      float4 w4 = wr[k4];
      acc += w4.x*hbuf[k4*4] + w4.y*hbuf[k4*4+1] + w4.z*hbuf[k4*4+2] + w4.w*hbuf[k4*4+3];
    }
    modb[b*256+c] = 1.f/(1.f + __expf(-acc));
  }
}

// ---------------- merged weight transforms to bf16 ----------------
__global__ __launch_bounds__(256) void k_wprep(const float* __restrict__ w1,
    const float* __restrict__ wsc, const float* __restrict__ w2,
    u16* __restrict__ w1t, u16* __restrict__ wsct, u16* __restrict__ w2t){
  int bx = blockIdx.x, ci = threadIdx.x;
  if (bx < 2304){
    int co = bx / 9, t = bx - co*9;
    w1t[(size_t)co*2304 + t*256 + ci] = f2bf(w1[(size_t)(co*256+ci)*9 + t]);
  } else if (bx < 2560){
    int i = (bx-2304)*256 + ci;
    wsct[i] = f2bf(wsc[i]);
  } else {
    int i = (bx-2560)*256 + ci;
    w2t[i] = f2bf(w2[i]);
  }
}

// ---------------- xm = x*mod, NCHW f32 -> NHWC bf16 ----------------
__global__ __launch_bounds__(256) void k_xm(const float* __restrict__ x, const float* __restrict__ modb,
                                            u16* __restrict__ xm){
  __shared__ __attribute__((aligned(16))) u16 tile[64*266];
  int pt = blockIdx.x, ct = blockIdx.y, tid = threadIdx.x;
  size_t P0 = (size_t)pt * 256;
  int b = pt >> 4;
  int rem = (pt & 15) << 8;
  int C0 = ct << 6;
  {
    int c = tid >> 2, q = tid & 3;
    const float* xp = x + ((size_t)(b*256 + C0 + c))*HW + rem;
    float mv = modb[b*256 + C0 + c];
    #pragma unroll
    for (int k=0;k<16;k++){
      int pos = q*64 + k*4;
      float4 v = *(const float4*)(xp + pos);
      u32 w0 = (u32)f2bf(v.x*mv) | ((u32)f2bf(v.y*mv) << 16);
      u32 w1 = (u32)f2bf(v.z*mv) | ((u32)f2bf(v.w*mv) << 16);
      u32* dst = (u32*)&tile[c*266 + pos];
      dst[0] = w0; dst[1] = w1;
    }
  }
  __syncthreads();
  {
    int g = tid & 7, p0 = tid >> 3;
    #pragma unroll
    for (int k=0;k<8;k++){
      int pos = p0 + k*32;
      u32 v0 = tile[(g*8+0)*266 + pos], v1 = tile[(g*8+1)*266 + pos];
      u32 v2 = tile[(g*8+2)*266 + pos], v3 = tile[(g*8+3)*266 + pos];
      u32 v4 = tile[(g*8+4)*266 + pos], v5 = tile[(g*8+5)*266 + pos];
      u32 v6 = tile[(g*8+6)*266 + pos], v7 = tile[(g*8+7)*266 + pos];
      uint4 pk;
      pk.x = v0 | (v1<<16); pk.y = v2 | (v3<<16);
      pk.z = v4 | (v5<<16); pk.w = v6 | (v7<<16);
      *(uint4*)(xm + (P0+pos)*CH + C0 + g*8) = pk;
    }
  }
}

// ---------------- GEMM epilogue: store y bf16 + per-mtile channel partials ----------------
// psum/psq layout: [channel][mtile] (MT stride) so k_bnstat reads coalesced.
__device__ __forceinline__ void epilogue_store(f32x4 (&acc)[4][4], int P0, int N0, int wm, int wn,
    int l15, int quad, int tid, int mt_blk, u16* __restrict__ y,
    float* __restrict__ psum, float* __restrict__ psq, float* redbuf){
  #pragma unroll
  for (int i=0;i<4;i++){
    int m = wm*64 + i*16 + quad*4;
    #pragma unroll
    for (int j=0;j<4;j++){
      int n = wn*64 + j*16 + l15;
      size_t base = ((size_t)(P0 + m))*CH + N0 + n;
      #pragma unroll
      for (int r=0;r<4;r++)
        y[base + (size_t)r*CH] = f2bf(acc[i][j][r]);
    }
  }
  #pragma unroll
  for (int j=0;j<4;j++){
    float a=0.f, b=0.f;
    #pragma unroll
    for (int i=0;i<4;i++)
      #pragma unroll
      for (int r=0;r<4;r++){ float v = acc[i][j][r]; a += v; b += v*v; }
    a += __shfl_xor(a,16); b += __shfl_xor(b,16);
    a += __shfl_xor(a,32); b += __shfl_xor(b,32);
    if (quad==0){
      int idx = (((wn*2+wm)*4 + j)*16 + l15)*2;
      redbuf[idx] = a; redbuf[idx+1] = b;
    }
  }
  __syncthreads();
  if (tid < 128){
    int n = tid; int wnn = n>>6, ntj=(n>>4)&3, li=n&15;
    int i0 = (((wnn*2+0)*4 + ntj)*16 + li)*2;
    int i1 = (((wnn*2+1)*4 + ntj)*16 + li)*2;
    psum[(size_t)(N0 + n)*MT + mt_blk] = redbuf[i0]   + redbuf[i1];
    psq [(size_t)(N0 + n)*MT + mt_blk] = redbuf[i0+1] + redbuf[i1+1];
  }
}

// ---------------- conv3x3 implicit GEMM ----------------
// R7: triple-buffered, prefetch-depth-2, COUNTED vmcnt + raw s_barrier (T4).
// R6 lesson: gload_lds vs reg-staging was perf-neutral (117.5us both, conflicts
// identical 9.4M -> conflicts are read-side; staging never critical). The real
// stall: __syncthreads drains vmcnt(0) each step, killing the prefetch. Now the
// wait is vmcnt(4) (allow the newest stage in flight); buffer read at step ks
// was staged at step ks-2 -> ~2 compute phases of latency cover. Stage issue is
// AFTER the barrier (barrier proves all waves consumed the buffer being
// overwritten: their ds_reads were lgkm-drained before they arrived).
__global__ __launch_bounds__(256) void k_conv3(const u16* __restrict__ xm, const u16* __restrict__ w1t,
    u16* __restrict__ y, float* __restrict__ psum, float* __restrict__ psq, const u16* __restrict__ zp){
  __shared__ __attribute__((aligned(16))) u16 As[3*4096];
  __shared__ __attribute__((aligned(16))) u16 Bs[3*4096];
  __shared__ __attribute__((aligned(16))) float redbuf[512];
  int bx = blockIdx.x;
  int mt_blk = ((bx >> 4) << 3) | (bx & 7);
  int nt_blk = (bx >> 3) & 1;
  int tid = threadIdx.x;
  int lane = tid & 63, wave = tid >> 6;
  int wm = wave & 1, wn = wave >> 1;
  int l15 = lane & 15, quad = lane >> 4;
  int P0 = mt_blk*128, N0 = nt_blk*128;
  int prow = tid >> 2, cg = tid & 3;
  // pre-swizzled source column-group: LDS slot (prow,cg) holds src cg^s(prow)
  int cgs = cg ^ (prow & 3) ^ ((prow >> 2) & 3);
  int rdsw = (quad ^ (l15 & 3) ^ ((l15 >> 2) & 3)) * 8;
  int rA[4], rB[4];
  #pragma unroll
  for (int i=0;i<4;i++){
    rA[i] = (wm*64 + i*16 + l15)*32 + rdsw;
    rB[i] = (wn*64 + i*16 + l15)*32 + rdsw;
  }
  const u16* b0base = w1t + (size_t)(N0 + prow)*2304 + cgs*8;
  const u16* b1base = w1t + (size_t)(N0 + prow + 64)*2304 + cgs*8;
  int P_0 = P0 + prow, P_1 = P0 + prow + 64;
  int h_0 = (P_0 >> 6) & 63, w_0 = P_0 & 63, bi0 = P_0 >> 12;
  int h_1 = (P_1 >> 6) & 63, w_1 = P_1 & 63, bi1 = P_1 >> 12;

  f32x4 acc[4][4];
  f32x4 zz = {0.f,0.f,0.f,0.f};
  #pragma unroll
  for (int i=0;i<4;i++)
    #pragma unroll
    for (int j=0;j<4;j++) acc[i][j] = zz;

  auto aptr0 = [&](int t)->const u16*{
    int dh = t/3 - 1, dw = t%3 - 1;
    int h2 = h_0 + dh, w2 = w_0 + dw;
    return (((unsigned)h2 < 64u) && ((unsigned)w2 < 64u))
        ? xm + (((size_t)bi0*HW + h2*64 + w2)*CH) + cgs*8 : zp + cgs*8;
  };
  auto aptr1 = [&](int t)->const u16*{
    int dh = t/3 - 1, dw = t%3 - 1;
    int h2 = h_1 + dh, w2 = w_1 + dw;
    return (((unsigned)h2 < 64u) && ((unsigned)w2 < 64u))
        ? xm + (((size_t)bi1*HW + h2*64 + w2)*CH) + cgs*8 : zp + cgs*8;
  };
  auto stage = [&](const u16* a0, const u16* a1, const u16* b0, const u16* b1, int bo){
    GLL16(a0, As + bo + wave*512);
    GLL16(a1, As + bo + 2048 + wave*512);
    GLL16(b0, Bs + bo + wave*512);
    GLL16(b1, Bs + bo + 2048 + wave*512);
  };

  // stage-cursor pointers (tap currently being staged)
  const u16 *sa0 = aptr0(0), *sa1 = aptr1(0);
  const u16 *sb0 = b0base,   *sb1 = b1base;
  const u16 *na0 = sa0, *na1 = sa1, *nb0 = sb0, *nb1 = sb1;  // next-tap

  // prologue: stage ks=0 -> buf0, ks=1 -> buf1 (8 loads in flight)
  stage(sa0,      sa1,      sb0,      sb1,      0);
  stage(sa0 + 32, sa1 + 32, sb0 + 32, sb1 + 32, 4096);
  int woff = 8192, roff = 0;

  for (int t=0; t<9; ++t){
    #pragma unroll
    for (int ci=0; ci<8; ++ci){
      // wait for current buffer's stage (issued 2 steps ago); keep newest in flight
      if (ci == 7){
        if (t == 8) { VM0(); } else { VM4(); }
      } else {
        VM4();
      }
      RBAR();
      // stage ksn = t*8+ci+2 into woff (skipped for the last two steps)
      if (t < 8 || ci < 6){
        const u16 *pa0s, *pa1s, *pb0s, *pb1s;
        if (ci < 6){
          pa0s = sa0 + (ci+2)*32; pa1s = sa1 + (ci+2)*32;
          pb0s = sb0 + (ci+2)*32; pb1s = sb1 + (ci+2)*32;
        } else if (ci == 6){
          na0 = aptr0(t+1); na1 = aptr1(t+1);
          nb0 = b0base + (t+1)*256; nb1 = b1base + (t+1)*256;
          pa0s = na0; pa1s = na1; pb0s = nb0; pb1s = nb1;
        } else { // ci == 7
          pa0s = na0 + 32; pa1s = na1 + 32;
          pb0s = nb0 + 32; pb1s = nb1 + 32;
        }
        stage(pa0s, pa1s, pb0s, pb1s, woff);
        woff = (woff == 8192) ? 0 : (woff + 4096);
      }
      if (ci == 7 && t < 8){ sa0 = na0; sa1 = na1; sb0 = nb0; sb1 = nb1; }
      // compute on current buffer
      bf16x8 af[4], bv[4];
      #pragma unroll
      for (int i=0;i<4;i++) af[i] = *(const bf16x8*)&As[roff + rA[i]];
      #pragma unroll
      for (int i=0;i<4;i++) bv[i] = *(const bf16x8*)&Bs[roff + rB[i]];
      #pragma unroll
      for (int i=0;i<4;i++)
        #pragma unroll
        for (int j=0;j<4;j++)
          acc[i][j] = __builtin_amdgcn_mfma_f32_16x16x32_bf16(af[i], bv[j], acc[i][j], 0, 0, 0);
      roff = (roff == 8192) ? 0 : (roff + 4096);
    }
  }
  __syncthreads();   // epilogue reuses redbuf; full sync before stores is cheap (once)
  epilogue_store(acc, P0, N0, wm, wn, l15, quad, tid, mt_blk, y, psum, psq, redbuf);
}

// ---------------- 1x1 conv GEMM (sc and conv2), triple-buffer counted-vmcnt ----------------
__global__ __launch_bounds__(256) void k_gemm1x1(const u16* __restrict__ A, const u16* __restrict__ Bw,
    u16* __restrict__ y, float* __restrict__ psum, float* __restrict__ psq){
  __shared__ __attribute__((aligned(16))) u16 As[3*4096];
  __shared__ __attribute__((aligned(16))) u16 Bs[3*4096];
  __shared__ __attribute__((aligned(16))) float redbuf[512];
  int bx = blockIdx.x;
  int mt_blk = ((bx >> 4) << 3) | (bx & 7);
  int nt_blk = (bx >> 3) & 1;
  int tid = threadIdx.x;
  int lane = tid & 63, wave = tid >> 6;
  int wm = wave & 1, wn = wave >> 1;
  int l15 = lane & 15, quad = lane >> 4;
  int P0 = mt_blk*128, N0 = nt_blk*128;
  int prow = tid >> 2, cg = tid & 3;
  int cgs = cg ^ (prow & 3) ^ ((prow >> 2) & 3);
  int rdsw = (quad ^ (l15 & 3) ^ ((l15 >> 2) & 3)) * 8;
  int rA[4], rB[4];
  #pragma unroll
  for (int i=0;i<4;i++){
    rA[i] = (wm*64 + i*16 + l15)*32 + rdsw;
    rB[i] = (wn*64 + i*16 + l15)*32 + rdsw;
  }
  const u16* a0p = A  + ((size_t)(P0 + prow))*CH + cgs*8;
  const u16* a1p = A  + ((size_t)(P0 + prow + 64))*CH + cgs*8;
  const u16* b0p = Bw + ((size_t)(N0 + prow))*CH + cgs*8;
  const u16* b1p = Bw + ((size_t)(N0 + prow + 64))*CH + cgs*8;

  f32x4 acc[4][4];
  f32x4 zz = {0.f,0.f,0.f,0.f};
  #pragma unroll
  for (int i=0;i<4;i++)
    #pragma unroll
    for (int j=0;j<4;j++) acc[i][j] = zz;

  auto stage = [&](int off, int bo){
    GLL16(a0p + off, As + bo + wave*512);
    GLL16(a1p + off, As + bo + 2048 + wave*512);
    GLL16(b0p + off, Bs + bo + wave*512);
    GLL16(b1p + off, Bs + bo + 2048 + wave*512);
  };

  stage(0, 0);
  stage(32, 4096);
  int woff = 8192, roff = 0;

  #pragma unroll
  for (int ci=0; ci<8; ++ci){
    if (ci == 7) { VM0(); } else { VM4(); }
    RBAR();
    if (ci < 6){
      stage((ci+2)*32, woff);
      woff = (woff == 8192) ? 0 : (woff + 4096);
    }
    bf16x8 af[4], bv[4];
    #pragma unroll
    for (int i=0;i<4;i++) af[i] = *(const bf16x8*)&As[roff + rA[i]];
    #pragma unroll
    for (int i=0;i<4;i++) bv[i] = *(const bf16x8*)&Bs[roff + rB[i]];
    #pragma unroll
    for (int i=0;i<4;i++)
      #pragma unroll
      for (int j=0;j<4;j++)
        acc[i][j] = __builtin_amdgcn_mfma_f32_16x16x32_bf16(af[i], bv[j], acc[i][j], 0, 0, 0);
    roff = (roff == 8192) ? 0 : (roff + 4096);
  }
  __syncthreads();
  epilogue_store(acc, P0, N0, wm, wn, l15, quad, tid, mt_blk, y, psum, psq, redbuf);
}

// ---------------- BN stat finalize: one block per channel, coalesced ----------------
__global__ __launch_bounds__(64) void k_bnstat(const float* __restrict__ psum, const float* __restrict__ psq,
    const float* __restrict__ g, const float* __restrict__ be,
    float* __restrict__ scale, float* __restrict__ shift){
  int c = blockIdx.x, t = threadIdx.x;
  const float* ps = psum + (size_t)c*MT;
  const float* pq = psq  + (size_t)c*MT;
  float s=0.f, q=0.f;
  #pragma unroll
  for (int i=0;i<8;i++){ s += ps[t + i*64]; q += pq[t + i*64]; }
  #pragma unroll
  for (int off=32; off>0; off>>=1){
    s += __shfl_down(s, off);
    q += __shfl_down(q, off);
  }
  if (t == 0){
    float mean = s * (1.f/65536.f);
    float var  = q * (1.f/65536.f) - mean*mean;
    float rstd = rsqrtf(var + 1e-5f);
    float sc = g[c]*rstd;
    scale[c] = sc;
    shift[c] = be[c] - mean*sc;
  }
}

// ---------------- bb1 = silu(bn1(y1)) elementwise on NHWC bf16 ----------------
__global__ __launch_bounds__(256) void k_bb(const u16* __restrict__ y1, const float* __restrict__ sc1,
    const float* __restrict__ sh1, u16* __restrict__ bb){
  __shared__ float sc[256], sh[256];
  int tid = threadIdx.x;
  sc[tid] = sc1[tid]; sh[tid] = sh1[tid];
  __syncthreads();
  size_t i = ((size_t)blockIdx.x*256 + tid)*8;
  int c0 = (int)(i & 255);
  uint4 v = *(const uint4*)(y1 + i);
  u32 a[4] = {v.x, v.y, v.z, v.w};
  u32 o[4];
  #pragma unroll
  for (int p=0;p<4;p++){
    float zl = sc[c0+2*p]*bflo(a[p]) + sh[c0+2*p];
    float zh = sc[c0+2*p+1]*bfhi(a[p]) + sh[c0+2*p+1];
    float ol = zl/(1.f+__expf(-zl));
    float oh = zh/(1.f+__expf(-zh));
    o[p] = (u32)f2bf(ol) | ((u32)f2bf(oh) << 16);
  }
  uint4 w; w.x=o[0]; w.y=o[1]; w.z=o[2]; w.w=o[3];
  *(uint4*)(bb + i) = w;
}

// ---------------- out = silu(bn2(y2)+bns(ysc)), NHWC bf16 -> NCHW f32 ----------------
__global__ __launch_bounds__(256) void k_final(const u16* __restrict__ y2, const u16* __restrict__ ysc,
    const float* __restrict__ sc2, const float* __restrict__ sh2,
    const float* __restrict__ scs, const float* __restrict__ shs,
    float* __restrict__ out){
  __shared__ __attribute__((aligned(16))) float tile[64*257];
  __shared__ float l2s[64], l2h[64], lss[64], lsh[64];
  int pt = blockIdx.x, ct = blockIdx.y, tid = threadIdx.x;
  int C0 = ct << 6;
  if (tid < 64){ l2s[tid]=sc2[C0+tid]; l2h[tid]=sh2[C0+tid]; lss[tid]=scs[C0+tid]; lsh[tid]=shs[C0+tid]; }
  __syncthreads();
  size_t P0 = (size_t)pt * 256;
  int b = pt >> 4; int rem = (pt & 15) << 8;
  {
    int g = tid & 7, p0 = tid >> 3;
    for (int k=0;k<8;k++){
      int pos = p0 + k*32;
      size_t off = (P0+pos)*CH + C0 + g*8;
      uint4 va = *(const uint4*)(y2 + off);
      uint4 vb = *(const uint4*)(ysc + off);
      u32 aa[4] = {va.x,va.y,va.z,va.w};
      u32 bv[4] = {vb.x,vb.y,vb.z,vb.w};
      #pragma unroll
      for (int p=0;p<4;p++){
        int c = g*8 + 2*p;
        float z0 = l2s[c]*bflo(aa[p]) + l2h[c] + lss[c]*bflo(bv[p]) + lsh[c];
        float z1 = l2s[c+1]*bfhi(aa[p]) + l2h[c+1] + lss[c+1]*bfhi(bv[p]) + lsh[c+1];
        tile[c*257 + pos]     = z0/(1.f+__expf(-z0));
        tile[(c+1)*257 + pos] = z1/(1.f+__expf(-z1));
      }
    }
  }
  __syncthreads();
  {
    int c = tid >> 2, q = tid & 3;
    float* op = out + ((size_t)(b*256 + C0 + c))*HW + rem;
    #pragma unroll
    for (int k=0;k<16;k++){
      int pos = q*64 + k*4;
      float4 v;
      v.x = tile[c*257 + pos];
      v.y = tile[c*257 + pos + 1];
      v.z = tile[c*257 + pos + 2];
      v.w = tile[c*257 + pos + 3];
      *(float4*)(op + pos) = v;
    }
  }
}

extern "C" void kernel_launch(void* const* d_in, const int* in_sizes, int n_in,
                              void* d_out, int out_size, void* d_ws, size_t ws_size,
                              hipStream_t stream){
  const float* x     = (const float*)d_in[0];
  const float* dce   = (const float*)d_in[1];
  const float* w_dce = (const float*)d_in[2];
  const float* b_dce = (const float*)d_in[3];
  const float* w_ch  = (const float*)d_in[4];
  const float* w_sh  = (const float*)d_in[5];
  const float* b_sh  = (const float*)d_in[6];
  const float* w_ex  = (const float*)d_in[7];
  const float* b_ex  = (const float*)d_in[8];
  const float* w_c1  = (const float*)d_in[9];
  const float* g1    = (const float*)d_in[10];
  const float* be1   = (const float*)d_in[11];
  const float* w_c2  = (const float*)d_in[12];
  const float* g2    = (const float*)d_in[13];
  const float* be2   = (const float*)d_in[14];
  const float* w_s   = (const float*)d_in[15];
  const float* gs    = (const float*)d_in[16];
  const float* bes   = (const float*)d_in[17];
  float* out = (float*)d_out;
  char* ws = (char*)d_ws;

  const size_t NB = (size_t)NPOS*CH*2;   // 32 MiB per bf16 tensor
  u16* xm  = (u16*)(ws);
  u16* y1  = (u16*)(ws + NB);
  u16* ysc = (u16*)(ws + 2*NB);
  u16* bb  = (u16*)(ws + 3*NB);
  char* p = ws + 4*NB;
  u16* w1t   = (u16*)p; p += (size_t)256*2304*2;
  u16* wsct  = (u16*)p; p += (size_t)256*256*2;
  u16* w2t   = (u16*)p; p += (size_t)256*256*2;
  float* statsx = (float*)p; p += (size_t)16*256*9*4;
  float* modb   = (float*)p; p += (size_t)16*256*4;
  float* p1s = (float*)p; p += (size_t)MT*256*4;
  float* p1q = (float*)p; p += (size_t)MT*256*4;
  float* pss = (float*)p; p += (size_t)MT*256*4;
  float* psqv= (float*)p; p += (size_t)MT*256*4;
  float* p2s = (float*)p; p += (size_t)MT*256*4;
  float* p2q = (float*)p; p += (size_t)MT*256*4;
  float* bn1sc = (float*)p; p += 1024;
  float* bn1sh = (float*)p; p += 1024;
  float* bnssc = (float*)p; p += 1024;
  float* bnssh = (float*)p; p += 1024;
  float* bn2sc = (float*)p; p += 1024;
  float* bn2sh = (float*)p; p += 1024;
  u16* zp = (u16*)p; p += 4096;

  hipMemsetAsync(zp, 0, 4096, stream);
  k_statsx<<<4096, 256, 0, stream>>>(x, statsx);
  k_wprep<<<2816, 256, 0, stream>>>(w_c1, w_s, w_c2, w1t, wsct, w2t);
  k_gate<<<16, 256, 0, stream>>>(dce, statsx, w_ch, w_dce, b_dce, w_sh, b_sh, w_ex, b_ex, modb);
  k_xm<<<dim3(256,4), 256, 0, stream>>>(x, modb, xm);
  k_conv3<<<1024, 256, 0, stream>>>(xm, w1t, y1, p1s, p1q, zp);
  k_bnstat<<<256, 64, 0, stream>>>(p1s, p1q, g1, be1, bn1sc, bn1sh);
  k_bb<<<8192, 256, 0, stream>>>(y1, bn1sc, bn1sh, bb);
  k_gemm1x1<<<1024, 256, 0, stream>>>(xm, wsct, ysc, pss, psqv);
  k_bnstat<<<256, 64, 0, stream>>>(pss, psqv, gs, bes, bnssc, bnssh);
  k_gemm1x1<<<1024, 256, 0, stream>>>(bb, w2t, y1 /*=y2*/, p2s, p2q);
  k_bnstat<<<256, 64, 0, stream>>>(p2s, p2q, g2, be2, bn2sc, bn2sh);
  k_final<<<dim3(256,4), 256, 0, stream>>>(y1, ysc, bn2sc, bn2sh, bnssc, bnssh, out);
}

// Round 3
// 393.343 us; speedup vs baseline: 1.0962x; 1.0821x over previous
//
#include <hip/hip_runtime.h>

typedef unsigned short u16;
typedef unsigned int   u32;
typedef __attribute__((ext_vector_type(8))) __bf16 bf16x8;
typedef __attribute__((ext_vector_type(4))) float  f32x4;

#define HW 4096
#define NPOS 65536
#define CH 256
#define MT 512    // workspace stride (allocation); NMT=256 used
#define NMT 256   // number of 256-row M tiles

__device__ __forceinline__ u16 f2bf(float f){
  u32 u = __float_as_uint(f);
  u += 0x7FFFu + ((u >> 16) & 1u);
  return (u16)(u >> 16);
}
__device__ __forceinline__ float bflo(u32 p){ return __uint_as_float(p << 16); }
__device__ __forceinline__ float bfhi(u32 p){ return __uint_as_float(p & 0xFFFF0000u); }

// global_load_lds width=16: per-lane GLOBAL src, wave-uniform LDS dst + lane*16B.
#define GLL16(g, l) __builtin_amdgcn_global_load_lds( \
    (__attribute__((address_space(1))) void*)(g), \
    (__attribute__((address_space(3))) void*)(l), 16, 0, 0)

#define VM8() asm volatile("s_waitcnt vmcnt(8)" ::: "memory")
#define VM4() asm volatile("s_waitcnt vmcnt(4)" ::: "memory")
#define VM0() asm volatile("s_waitcnt vmcnt(0)" ::: "memory")
#define BARX() do { __builtin_amdgcn_s_barrier(); __builtin_amdgcn_sched_barrier(0); } while(0)

// ---------------- x plane stats: total, edge rows/cols, corners ----------------
__global__ __launch_bounds__(256) void k_statsx(const float* __restrict__ x, float* __restrict__ stats){
  int bc = blockIdx.x; int tid = threadIdx.x;
  const float* xp = x + (size_t)bc * HW;
  float S=0.f, r0=0.f, r1=0.f, c0=0.f, c1=0.f;
  #pragma unroll
  for (int k=0;k<4;k++){
    int i4 = tid + k*256;
    float4 v = ((const float4*)xp)[i4];
    int pos = i4*4; int h = pos>>6; int wb = pos&63;
    float sv = v.x+v.y+v.z+v.w;
    S += sv;
    if (h==0)  r0 += sv;
    if (h==63) r1 += sv;
    if (wb==0)  c0 += v.x;
    if (wb==60) c1 += v.w;
  }
  __shared__ float red[4][5];
  #pragma unroll
  for (int off=32; off>0; off>>=1){
    S  += __shfl_down(S, off);
    r0 += __shfl_down(r0, off);
    r1 += __shfl_down(r1, off);
    c0 += __shfl_down(c0, off);
    c1 += __shfl_down(c1, off);
  }
  if ((tid & 63) == 0){
    int w = tid >> 6;
    red[w][0]=S; red[w][1]=r0; red[w][2]=r1; red[w][3]=c0; red[w][4]=c1;
  }
  __syncthreads();
  if (tid == 0){
    float* o = stats + (size_t)bc * 9;
    for (int j=0;j<5;j++) o[j] = red[0][j]+red[1][j]+red[2][j]+red[3][j];
    o[5] = xp[0];    // x[0][0]
    o[6] = xp[63];   // x[0][63]
    o[7] = xp[4032]; // x[63][0]
    o[8] = xp[4095]; // x[63][63]
  }
}

// ---------------- fused modulation gate: one block per batch element ----------------
__global__ __launch_bounds__(256) void k_gate(const float* __restrict__ dce,
    const float* __restrict__ stats, const float* __restrict__ wch,
    const float* __restrict__ w_dce, const float* __restrict__ b_dce,
    const float* __restrict__ w_sh, const float* __restrict__ b_sh,
    const float* __restrict__ w_ex, const float* __restrict__ b_ex,
    float* __restrict__ modb){
  int b = blockIdx.x, tid = threadIdx.x;
  __shared__ float pl[128];
  __shared__ float mbuf[256];
  __shared__ float hbuf[128];
  __shared__ float ptmp[256];
  {
    int k = tid & 127, half = tid >> 7;
    const float* p = dce + (size_t)b*12800 + half*50*128 + k;
    float s = 0.f;
    #pragma unroll 5
    for (int l=0;l<50;l++) s += p[l*128];
    ptmp[tid] = s;
  }
  __syncthreads();
  if (tid < 128) pl[tid] = (ptmp[tid] + ptmp[tid+128]) * 0.01f;
  __syncthreads();
  {
    int c = tid;
    const float* st = stats + (size_t)(b*256+c)*9;
    float S=st[0], r0=st[1], r1=st[2], cc0=st[3], cc1=st[4];
    float x00=st[5], x0W=st[6], xH0=st[7], xHW=st[8];
    float acc = 0.f;
    #pragma unroll
    for (int t=0;t<9;t++){
      int dh = t/3 - 1, dw = t%3 - 1;
      float R = (dh==1)? r0 : (dh==-1)? r1 : 0.f;
      float Cc = (dw==1)? cc0 : (dw==-1)? cc1 : 0.f;
      float X = 0.f;
      if (dh==1 && dw==1) X = x00;
      else if (dh==1 && dw==-1) X = x0W;
      else if (dh==-1 && dw==1) X = xH0;
      else if (dh==-1 && dw==-1) X = xHW;
      acc += wch[c*9+t] * (S - R - Cc + X);
    }
    float sp_ = acc * (1.f/4096.f);
    float dp = b_dce[c];
    const float4* wr = (const float4*)(w_dce + c*128);
    #pragma unroll 8
    for (int k4=0;k4<32;k4++){
      float4 w4 = wr[k4];
      dp += w4.x*pl[k4*4] + w4.y*pl[k4*4+1] + w4.z*pl[k4*4+2] + w4.w*pl[k4*4+3];
    }
    mbuf[c] = sp_ * dp;
  }
  __syncthreads();
  if (tid < 128){
    int j = tid;
    float acc = b_sh[j];
    const float4* wr = (const float4*)(w_sh + j*256);
    #pragma unroll 8
    for (int k4=0;k4<64;k4++){
      float4 w4 = wr[k4];
      acc += w4.x*mbuf[k4*4] + w4.y*mbuf[k4*4+1] + w4.z*mbuf[k4*4+2] + w4.w*mbuf[k4*4+3];
    }
    hbuf[j] = fmaxf(acc, 0.f);
  }
  __syncthreads();
  {
    int c = tid;
    float acc = b_ex[c];
    const float4* wr = (const float4*)(w_ex + c*128);
    #pragma unroll 8
    for (int k4=0;k4<32;k4++){
      float4 w4 = wr[k4];
      acc += w4.x*hbuf[k4*4] + w4.y*hbuf[k4*4+1] + w4.z*hbuf[k4*4+2] + w4.w*hbuf[k4*4+3];
    }
    modb[b*256+c] = 1.f/(1.f + __expf(-acc));
  }
}

// ---------------- merged weight transforms to bf16 ----------------
__global__ __launch_bounds__(256) void k_wprep(const float* __restrict__ w1,
    const float* __restrict__ wsc, const float* __restrict__ w2,
    u16* __restrict__ w1t, u16* __restrict__ wsct, u16* __restrict__ w2t){
  int bx = blockIdx.x, ci = threadIdx.x;
  if (bx < 2304){
    int co = bx / 9, t = bx - co*9;
    w1t[(size_t)co*2304 + t*256 + ci] = f2bf(w1[(size_t)(co*256+ci)*9 + t]);
  } else if (bx < 2560){
    int i = (bx-2304)*256 + ci;
    wsct[i] = f2bf(wsc[i]);
  } else {
    int i = (bx-2560)*256 + ci;
    w2t[i] = f2bf(w2[i]);
  }
}

// ---------------- xm = x*mod, NCHW f32 -> NHWC bf16 ----------------
__global__ __launch_bounds__(256) void k_xm(const float* __restrict__ x, const float* __restrict__ modb,
                                            u16* __restrict__ xm){
  __shared__ __attribute__((aligned(16))) u16 tile[64*266];
  int pt = blockIdx.x, ct = blockIdx.y, tid = threadIdx.x;
  size_t P0 = (size_t)pt * 256;
  int b = pt >> 4;
  int rem = (pt & 15) << 8;
  int C0 = ct << 6;
  {
    int c = tid >> 2, q = tid & 3;
    const float* xp = x + ((size_t)(b*256 + C0 + c))*HW + rem;
    float mv = modb[b*256 + C0 + c];
    #pragma unroll
    for (int k=0;k<16;k++){
      int pos = q*64 + k*4;
      float4 v = *(const float4*)(xp + pos);
      u32 w0 = (u32)f2bf(v.x*mv) | ((u32)f2bf(v.y*mv) << 16);
      u32 w1 = (u32)f2bf(v.z*mv) | ((u32)f2bf(v.w*mv) << 16);
      u32* dst = (u32*)&tile[c*266 + pos];
      dst[0] = w0; dst[1] = w1;
    }
  }
  __syncthreads();
  {
    int g = tid & 7, p0 = tid >> 3;
    #pragma unroll
    for (int k=0;k<8;k++){
      int pos = p0 + k*32;
      u32 v0 = tile[(g*8+0)*266 + pos], v1 = tile[(g*8+1)*266 + pos];
      u32 v2 = tile[(g*8+2)*266 + pos], v3 = tile[(g*8+3)*266 + pos];
      u32 v4 = tile[(g*8+4)*266 + pos], v5 = tile[(g*8+5)*266 + pos];
      u32 v6 = tile[(g*8+6)*266 + pos], v7 = tile[(g*8+7)*266 + pos];
      uint4 pk;
      pk.x = v0 | (v1<<16); pk.y = v2 | (v3<<16);
      pk.z = v4 | (v5<<16); pk.w = v6 | (v7<<16);
      *(uint4*)(xm + (P0+pos)*CH + C0 + g*8) = pk;
    }
  }
}

// ---------------- 256x256-tile 8-wave multi-phase GEMM (conv3x3 + 1x1) ----------------
// R8: full structural port to the 256^2 counted-vmcnt schedule (m198/m201 class).
// - 8 waves (2M x 4N), 512 thr, per-wave output 128x64, acc = f32x4[8][4].
// - K-tile = 32; LDS = 4-set ring (4 x (A 16KB + B 16KB)) = 128KB; stage kt+3
//   while computing kt -> ~6 phases of latency cover; vmcnt(8) ONCE per K-tile
//   (tail: 8/4/0 by exact in-flight ledger); raw s_barrier only (no vmcnt(0)
//   drain in the loop -- R1/R2 showed the 2-phase drain structure is the wall).
// - Swizzle (row stride 64B): byte P = L ^ ((L>>9)&1)<<5 ^ ((L>>8)&1)<<4.
//   gload_lds writes linear; INVERSE swizzle on the global source (kb), same
//   XOR on the read side (lane-const: row bits 2,3 == l15 bits 2,3). Rule #21.
// - setprio(1) around MFMA (T5 -- in-regime now), 2 barriers/phase (recycle guard).
template<int NTAPS>
__global__ __launch_bounds__(512, 2) void k_gemm8p(const u16* __restrict__ A,
    const u16* __restrict__ Bw, u16* __restrict__ y,
    float* __restrict__ psum, float* __restrict__ psq, const u16* __restrict__ zp){
  constexpr int KTOT = NTAPS*256;
  constexpr int NT = KTOT/32;          // K-tiles
  __shared__ __attribute__((aligned(16))) u16 SH[65536];   // 128 KiB: A 4x8192, B 4x8192 (u16)
  int tid = threadIdx.x;
  int lane = tid & 63, wave = tid >> 6;
  int wm = wave >> 2, wn = wave & 3;
  int l15 = lane & 15, quad = lane >> 4;
  int mt = blockIdx.x;
  int P0 = mt*256;

  // read-side swizzled offsets (u16 units)
  int rdx   = (((l15>>3)&1)<<4) | (((l15>>2)&1)<<3);
  int kphys = (quad*8) ^ rdx;
  int aoff  = (wm*128 + l15)*32 + kphys;          // + set*8192 + q*2048 + i4*512
  int boff  = 32768 + (wn*64 + l15)*32 + kphys;   // + set*8192 + j*512

  // staging decode: thread writes linear 16B block #tid of the half-tile;
  // inverse swizzle -> source row = tid>>2 (fixed), k-block kb
  int pr = tid >> 2;
  int kb = (tid&3) ^ ((((tid>>5)&1)<<1) | ((tid>>4)&1));
  int k0 = kb*8;
  int pos0 = P0 + pr, pos1 = P0 + 128 + pr;
  int hh0 = (pos0>>6)&63, ww0 = pos0&63;
  int hh1 = (pos1>>6)&63, ww1 = pos1&63;

  f32x4 acc[8][4];
  f32x4 zz = {0.f,0.f,0.f,0.f};
  #pragma unroll
  for (int i=0;i<8;i++)
    #pragma unroll
    for (int j=0;j<4;j++) acc[i][j] = zz;

  auto stageA = [&](int ktn){
    int set = ktn & 3;
    if constexpr (NTAPS == 9){
      int tap = ktn >> 3;
      int t3 = tap/3;
      int dh = t3 - 1, dw = (tap - t3*3) - 1;
      int d = dh*64 + dw;
      int coff = ((ktn & 7)*32) + k0;
      bool ok0 = ((unsigned)(hh0+dh) < 64u) && ((unsigned)(ww0+dw) < 64u);
      bool ok1 = ((unsigned)(hh1+dh) < 64u) && ((unsigned)(ww1+dw) < 64u);
      const u16* s0 = ok0 ? A + (size_t)(pos0 + d)*CH + coff : zp + coff;
      const u16* s1 = ok1 ? A + (size_t)(pos1 + d)*CH + coff : zp + coff;
      GLL16(s0, SH + set*8192 + wave*512);
      GLL16(s1, SH + set*8192 + 4096 + wave*512);
    } else {
      const u16* s0 = A + (size_t)pos0*CH + ktn*32 + k0;
      const u16* s1 = A + (size_t)pos1*CH + ktn*32 + k0;
      GLL16(s0, SH + set*8192 + wave*512);
      GLL16(s1, SH + set*8192 + 4096 + wave*512);
    }
  };
  auto stageB = [&](int ktn){
    int set = ktn & 3;
    const u16* s0 = Bw + (size_t)pr*KTOT + ktn*32 + k0;
    const u16* s1 = Bw + (size_t)(pr+128)*KTOT + ktn*32 + k0;
    GLL16(s0, SH + 32768 + set*8192 + wave*512);
    GLL16(s1, SH + 32768 + set*8192 + 4096 + wave*512);
  };

  // prologue: stage kt 0,1,2 (12 loads/thread); need kt0 -> vmcnt(8)
  stageA(0); stageB(0);
  stageA(1); stageB(1);
  stageA(2); stageB(2);
  VM8();
  BARX();

  for (int w = 0; w < NT; ++w){
    int sb = (w & 3)*8192;
    bf16x8 af[4], bv[4];
    // ---- phase 0: rows [wm*128, +64) ----
    #pragma unroll
    for (int i=0;i<4;i++) af[i] = *(const bf16x8*)&SH[sb + aoff + i*512];
    #pragma unroll
    for (int j=0;j<4;j++) bv[j] = *(const bf16x8*)&SH[sb + boff + j*512];
    if (w+3 < NT) stageA(w+3);
    BARX();
    __builtin_amdgcn_s_setprio(1);
    #pragma unroll
    for (int i=0;i<4;i++)
      #pragma unroll
      for (int j=0;j<4;j++)
        acc[i][j] = __builtin_amdgcn_mfma_f32_16x16x32_bf16(af[i], bv[j], acc[i][j], 0, 0, 0);
    __builtin_amdgcn_s_setprio(0);
    BARX();
    // ---- phase 1: rows [wm*128+64, +64); bv reused ----
    #pragma unroll
    for (int i=0;i<4;i++) af[i] = *(const bf16x8*)&SH[sb + aoff + 2048 + i*512];
    if (w+3 < NT) stageB(w+3);
    if (w < NT-3)      { VM8(); }
    else if (w == NT-3){ VM4(); }
    else if (w == NT-2){ VM0(); }
    BARX();
    __builtin_amdgcn_s_setprio(1);
    #pragma unroll
    for (int i=0;i<4;i++)
      #pragma unroll
      for (int j=0;j<4;j++)
        acc[4+i][j] = __builtin_amdgcn_mfma_f32_16x16x32_bf16(af[i], bv[j], acc[4+i][j], 0, 0, 0);
    __builtin_amdgcn_s_setprio(0);
    BARX();
  }

  // ---- epilogue: y stores + per-mtile channel partials ----
  #pragma unroll
  for (int i=0;i<8;i++){
    int m = wm*128 + i*16 + quad*4;
    #pragma unroll
    for (int j=0;j<4;j++){
      int n = wn*64 + j*16 + l15;
      size_t base = ((size_t)(P0 + m))*CH + n;
      #pragma unroll
      for (int r=0;r<4;r++)
        y[base + (size_t)r*CH] = f2bf(acc[i][j][r]);
    }
  }
  float* SHf = (float*)SH;   // safe: loop-end barrier passed, vmcnt drained
  #pragma unroll
  for (int j=0;j<4;j++){
    float a=0.f, b=0.f;
    #pragma unroll
    for (int i=0;i<8;i++)
      #pragma unroll
      for (int r=0;r<4;r++){ float v = acc[i][j][r]; a += v; b += v*v; }
    a += __shfl_xor(a,16); b += __shfl_xor(b,16);
    a += __shfl_xor(a,32); b += __shfl_xor(b,32);
    if (quad==0){
      int idx = ((wave*4 + j)*16 + l15)*2;
      SHf[idx] = a; SHf[idx+1] = b;
    }
  }
  __syncthreads();
  if (tid < 256){
    int n = tid; int wnn = n>>6; int j = (n>>4)&3; int li = n&15;
    int i0 = (((wnn)*4 + j)*16 + li)*2;        // wm=0 wave = wn
    int i1 = (((4+wnn)*4 + j)*16 + li)*2;      // wm=1 wave = 4+wn
    psum[(size_t)n*NMT + mt] = SHf[i0] + SHf[i1];
    psq [(size_t)n*NMT + mt] = SHf[i0+1] + SHf[i1+1];
  }
}

// ---------------- BN stat finalize: one block per channel, coalesced ----------------
__global__ __launch_bounds__(64) void k_bnstat(const float* __restrict__ psum, const float* __restrict__ psq,
    const float* __restrict__ g, const float* __restrict__ be,
    float* __restrict__ scale, float* __restrict__ shift){
  int c = blockIdx.x, t = threadIdx.x;
  const float* ps = psum + (size_t)c*NMT;
  const float* pq = psq  + (size_t)c*NMT;
  float s=0.f, q=0.f;
  #pragma unroll
  for (int i=0;i<4;i++){ s += ps[t + i*64]; q += pq[t + i*64]; }
  #pragma unroll
  for (int off=32; off>0; off>>=1){
    s += __shfl_down(s, off);
    q += __shfl_down(q, off);
  }
  if (t == 0){
    float mean = s * (1.f/65536.f);
    float var  = q * (1.f/65536.f) - mean*mean;
    float rstd = rsqrtf(var + 1e-5f);
    float sc = g[c]*rstd;
    scale[c] = sc;
    shift[c] = be[c] - mean*sc;
  }
}

// ---------------- bb1 = silu(bn1(y1)) elementwise on NHWC bf16 ----------------
__global__ __launch_bounds__(256) void k_bb(const u16* __restrict__ y1, const float* __restrict__ sc1,
    const float* __restrict__ sh1, u16* __restrict__ bb){
  __shared__ float sc[256], sh[256];
  int tid = threadIdx.x;
  sc[tid] = sc1[tid]; sh[tid] = sh1[tid];
  __syncthreads();
  size_t i = ((size_t)blockIdx.x*256 + tid)*8;
  int c0 = (int)(i & 255);
  uint4 v = *(const uint4*)(y1 + i);
  u32 a[4] = {v.x, v.y, v.z, v.w};
  u32 o[4];
  #pragma unroll
  for (int p=0;p<4;p++){
    float zl = sc[c0+2*p]*bflo(a[p]) + sh[c0+2*p];
    float zh = sc[c0+2*p+1]*bfhi(a[p]) + sh[c0+2*p+1];
    float ol = zl/(1.f+__expf(-zl));
    float oh = zh/(1.f+__expf(-zh));
    o[p] = (u32)f2bf(ol) | ((u32)f2bf(oh) << 16);
  }
  uint4 w; w.x=o[0]; w.y=o[1]; w.z=o[2]; w.w=o[3];
  *(uint4*)(bb + i) = w;
}

// ---------------- out = silu(bn2(y2)+bns(ysc)), NHWC bf16 -> NCHW f32 ----------------
__global__ __launch_bounds__(256) void k_final(const u16* __restrict__ y2, const u16* __restrict__ ysc,
    const float* __restrict__ sc2, const float* __restrict__ sh2,
    const float* __restrict__ scs, const float* __restrict__ shs,
    float* __restrict__ out){
  __shared__ __attribute__((aligned(16))) float tile[64*257];
  __shared__ float l2s[64], l2h[64], lss[64], lsh[64];
  int pt = blockIdx.x, ct = blockIdx.y, tid = threadIdx.x;
  int C0 = ct << 6;
  if (tid < 64){ l2s[tid]=sc2[C0+tid]; l2h[tid]=sh2[C0+tid]; lss[tid]=scs[C0+tid]; lsh[tid]=shs[C0+tid]; }
  __syncthreads();
  size_t P0 = (size_t)pt * 256;
  int b = pt >> 4; int rem = (pt & 15) << 8;
  {
    int g = tid & 7, p0 = tid >> 3;
    for (int k=0;k<8;k++){
      int pos = p0 + k*32;
      size_t off = (P0+pos)*CH + C0 + g*8;
      uint4 va = *(const uint4*)(y2 + off);
      uint4 vb = *(const uint4*)(ysc + off);
      u32 aa[4] = {va.x,va.y,va.z,va.w};
      u32 bv[4] = {vb.x,vb.y,vb.z,vb.w};
      #pragma unroll
      for (int p=0;p<4;p++){
        int c = g*8 + 2*p;
        float z0 = l2s[c]*bflo(aa[p]) + l2h[c] + lss[c]*bflo(bv[p]) + lsh[c];
        float z1 = l2s[c+1]*bfhi(aa[p]) + l2h[c+1] + lss[c+1]*bfhi(bv[p]) + lsh[c+1];
        tile[c*257 + pos]     = z0/(1.f+__expf(-z0));
        tile[(c+1)*257 + pos] = z1/(1.f+__expf(-z1));
      }
    }
  }
  __syncthreads();
  {
    int c = tid >> 2, q = tid & 3;
    float* op = out + ((size_t)(b*256 + C0 + c))*HW + rem;
    #pragma unroll
    for (int k=0;k<16;k++){
      int pos = q*64 + k*4;
      float4 v;
      v.x = tile[c*257 + pos];
      v.y = tile[c*257 + pos + 1];
      v.z = tile[c*257 + pos + 2];
      v.w = tile[c*257 + pos + 3];
      *(float4*)(op + pos) = v;
    }
  }
}

extern "C" void kernel_launch(void* const* d_in, const int* in_sizes, int n_in,
                              void* d_out, int out_size, void* d_ws, size_t ws_size,
                              hipStream_t stream){
  const float* x     = (const float*)d_in[0];
  const float* dce   = (const float*)d_in[1];
  const float* w_dce = (const float*)d_in[2];
  const float* b_dce = (const float*)d_in[3];
  const float* w_ch  = (const float*)d_in[4];
  const float* w_sh  = (const float*)d_in[5];
  const float* b_sh  = (const float*)d_in[6];
  const float* w_ex  = (const float*)d_in[7];
  const float* b_ex  = (const float*)d_in[8];
  const float* w_c1  = (const float*)d_in[9];
  const float* g1    = (const float*)d_in[10];
  const float* be1   = (const float*)d_in[11];
  const float* w_c2  = (const float*)d_in[12];
  const float* g2    = (const float*)d_in[13];
  const float* be2   = (const float*)d_in[14];
  const float* w_s   = (const float*)d_in[15];
  const float* gs    = (const float*)d_in[16];
  const float* bes   = (const float*)d_in[17];
  float* out = (float*)d_out;
  char* ws = (char*)d_ws;

  const size_t NB = (size_t)NPOS*CH*2;   // 32 MiB per bf16 tensor
  u16* xm  = (u16*)(ws);
  u16* y1  = (u16*)(ws + NB);
  u16* ysc = (u16*)(ws + 2*NB);
  u16* bb  = (u16*)(ws + 3*NB);
  char* p = ws + 4*NB;
  u16* w1t   = (u16*)p; p += (size_t)256*2304*2;
  u16* wsct  = (u16*)p; p += (size_t)256*256*2;
  u16* w2t   = (u16*)p; p += (size_t)256*256*2;
  float* statsx = (float*)p; p += (size_t)16*256*9*4;
  float* modb   = (float*)p; p += (size_t)16*256*4;
  float* p1s = (float*)p; p += (size_t)MT*256*4;
  float* p1q = (float*)p; p += (size_t)MT*256*4;
  float* pss = (float*)p; p += (size_t)MT*256*4;
  float* psqv= (float*)p; p += (size_t)MT*256*4;
  float* p2s = (float*)p; p += (size_t)MT*256*4;
  float* p2q = (float*)p; p += (size_t)MT*256*4;
  float* bn1sc = (float*)p; p += 1024;
  float* bn1sh = (float*)p; p += 1024;
  float* bnssc = (float*)p; p += 1024;
  float* bnssh = (float*)p; p += 1024;
  float* bn2sc = (float*)p; p += 1024;
  float* bn2sh = (float*)p; p += 1024;
  u16* zp = (u16*)p; p += 4096;

  hipMemsetAsync(zp, 0, 4096, stream);
  k_statsx<<<4096, 256, 0, stream>>>(x, statsx);
  k_wprep<<<2816, 256, 0, stream>>>(w_c1, w_s, w_c2, w1t, wsct, w2t);
  k_gate<<<16, 256, 0, stream>>>(dce, statsx, w_ch, w_dce, b_dce, w_sh, b_sh, w_ex, b_ex, modb);
  k_xm<<<dim3(256,4), 256, 0, stream>>>(x, modb, xm);
  k_gemm8p<9><<<256, 512, 0, stream>>>(xm, w1t, y1, p1s, p1q, zp);
  k_bnstat<<<256, 64, 0, stream>>>(p1s, p1q, g1, be1, bn1sc, bn1sh);
  k_bb<<<8192, 256, 0, stream>>>(y1, bn1sc, bn1sh, bb);
  k_gemm8p<1><<<256, 512, 0, stream>>>(xm, wsct, ysc, pss, psqv, zp);
  k_bnstat<<<256, 64, 0, stream>>>(pss, psqv, gs, bes, bnssc, bnssh);
  k_gemm8p<1><<<256, 512, 0, stream>>>(bb, w2t, y1 /*=y2*/, p2s, p2q, zp);
  k_bnstat<<<256, 64, 0, stream>>>(p2s, p2q, g2, be2, bn2sc, bn2sh);
  k_final<<<dim3(256,4), 256, 0, stream>>>(y1, ysc, bn2sc, bn2sh, bnssc, bnssh, out);
}